// Round 1
// baseline (547.668 us; speedup 1.0000x reference)
//
#include <hip/hip_runtime.h>
#include <cstddef>

#define N 8192
#define D 256
#define BI 128
#define BJ 128
#define KT 64
#define SA 68          // LDS row stride in floats: 64 + 4 pad (272 B, 16B-aligned)
#define SPLITS 8
#define JRANGE (N / SPLITS)   // 1024

// ---------------- K1: copy e_actv and e_ap into out[0 : 2*N*D) ----------------
__global__ void copy_kernel(const float4* __restrict__ a, const float4* __restrict__ p,
                            float4* __restrict__ out) {
    int idx = blockIdx.x * blockDim.x + threadIdx.x;
    const int total = N * D / 4;   // 524288 float4 per input
    if (idx < total) out[idx] = a[idx];
    else             out[idx] = p[idx - total];
}

// ---------------- K2: squared row norms of e_actv ----------------
__global__ void sqnorm_kernel(const float* __restrict__ e, float* __restrict__ sq) {
    int row = blockIdx.x;
    int t = threadIdx.x;                   // 64 threads, one float4 per lane
    const float4* r4 = (const float4*)(e + (size_t)row * D);
    float4 v = r4[t];
    float s = v.x * v.x + v.y * v.y + v.z * v.z + v.w * v.w;
    #pragma unroll
    for (int off = 32; off; off >>= 1) s += __shfl_down(s, off);
    if (t == 0) sq[row] = s;
}

// ---------------- K3: fused pairwise-dot + masked argmin (partial per split) ----------------
// key(i,j) = sq[j] - 2*dot(e[i], e[j])  — same argmin as the reference distance.
__launch_bounds__(256, 2)
__global__ void argmin_kernel(const float* __restrict__ E, const int* __restrict__ host,
                              const float* __restrict__ sq,
                              float* __restrict__ pV, int* __restrict__ pI) {
    __shared__ __align__(16) float smem[2 * BI * SA + BI + BI];
    float* A_s = smem;                       // [128][68]
    float* B_s = smem + BI * SA;             // [128][68]
    float* sqB_s = smem + 2 * BI * SA;       // [128]
    int*   hostB_s = (int*)(smem + 2 * BI * SA + BI); // [128]

    const int tile  = blockIdx.x / SPLITS;   // 0..63  (row tile)
    const int split = blockIdx.x % SPLITS;   // 0..7   (j-range slice)
    const int i0 = tile * BI;
    const int tid = threadIdx.x;
    const int tx = tid & 15, ty = tid >> 4;

    int hostA[8];
    #pragma unroll
    for (int r = 0; r < 8; r++) hostA[r] = host[i0 + ty + 16 * r];

    float best[8];
    int bidx[8];
    #pragma unroll
    for (int r = 0; r < 8; r++) { best[r] = 3.0e38f; bidx[r] = 0x7fffffff; }

    for (int jc = 0; jc < JRANGE; jc += BJ) {
        const int j0 = split * JRANGE + jc;
        float acc[8][8];
        #pragma unroll
        for (int r = 0; r < 8; r++)
            #pragma unroll
            for (int c = 0; c < 8; c++) acc[r][c] = 0.0f;

        for (int kt = 0; kt < D; kt += KT) {
            __syncthreads();   // protect LDS from readers of the previous stage
            // stage A(128x64) and B(128x64): 2048 float4 each, 8 per thread each
            #pragma unroll
            for (int q = 0; q < 8; q++) {
                int f = tid + q * 256;       // 0..2047
                int row = f >> 4;            // 0..127
                int kq = f & 15;             // float4 index within the 64-wide k chunk
                float4 va = *(const float4*)&E[(size_t)(i0 + row) * D + kt + kq * 4];
                *(float4*)&A_s[row * SA + kq * 4] = va;
                float4 vb = *(const float4*)&E[(size_t)(j0 + row) * D + kt + kq * 4];
                *(float4*)&B_s[row * SA + kq * 4] = vb;
            }
            if (kt == 0 && tid < BI) {
                sqB_s[tid] = sq[j0 + tid];
                hostB_s[tid] = host[j0 + tid];
            }
            __syncthreads();

            #pragma unroll 2
            for (int kq = 0; kq < 16; kq++) {
                float4 a4[8], b4[8];
                #pragma unroll
                for (int r = 0; r < 8; r++)
                    a4[r] = *(const float4*)&A_s[(ty + 16 * r) * SA + kq * 4];
                #pragma unroll
                for (int c = 0; c < 8; c++)
                    b4[c] = *(const float4*)&B_s[(tx + 16 * c) * SA + kq * 4];
                #pragma unroll
                for (int r = 0; r < 8; r++)
                    #pragma unroll
                    for (int c = 0; c < 8; c++) {
                        acc[r][c] = fmaf(a4[r].x, b4[c].x, acc[r][c]);
                        acc[r][c] = fmaf(a4[r].y, b4[c].y, acc[r][c]);
                        acc[r][c] = fmaf(a4[r].z, b4[c].z, acc[r][c]);
                        acc[r][c] = fmaf(a4[r].w, b4[c].w, acc[r][c]);
                    }
            }
        }

        // epilogue: masked argmin update (strict < keeps lowest j on ties since c ascends)
        #pragma unroll
        for (int r = 0; r < 8; r++) {
            const int ig = i0 + ty + 16 * r;
            #pragma unroll
            for (int c = 0; c < 8; c++) {
                const int jl = tx + 16 * c;
                const int jg = j0 + jl;
                float key = sqB_s[jl] - 2.0f * acc[r][c];
                bool masked = (hostB_s[jl] == hostA[r]) || (jg == ig);
                if (!masked && key < best[r]) { best[r] = key; bidx[r] = jg; }
            }
        }
    }

    // block-level reduction across tx (16 candidates per row), alias scratch onto A_s
    __syncthreads();
    float* redV = A_s;                 // [128][16]
    int*   redI = (int*)(A_s + BI * 16);
    #pragma unroll
    for (int r = 0; r < 8; r++) {
        int il = ty + 16 * r;
        redV[il * 16 + tx] = best[r];
        redI[il * 16 + tx] = bidx[r];
    }
    __syncthreads();
    if (tid < BI) {
        float bv = 3.1e38f; int bi = 0x7fffffff;
        for (int t = 0; t < 16; t++) {
            float v = redV[tid * 16 + t];
            int ix = redI[tid * 16 + t];
            if (v < bv || (v == bv && ix < bi)) { bv = v; bi = ix; }
        }
        pV[(size_t)(i0 + tid) * SPLITS + split] = bv;
        pI[(size_t)(i0 + tid) * SPLITS + split] = bi;
    }
}

// ---------------- K4: reduce split partials and gather e_an rows ----------------
__global__ void finalize_kernel(const float* __restrict__ pV, const int* __restrict__ pI,
                                const float* __restrict__ E, float* __restrict__ out_an) {
    int row = blockIdx.x;
    int t = threadIdx.x;   // 64
    __shared__ int sidx;
    if (t == 0) {
        float bv = 3.2e38f; int bi = 0x7fffffff;
        // splits cover ascending disjoint j-ranges; strict < keeps the lowest j
        for (int s = 0; s < SPLITS; s++) {
            float v = pV[(size_t)row * SPLITS + s];
            int ix = pI[(size_t)row * SPLITS + s];
            if (v < bv || (v == bv && ix < bi)) { bv = v; bi = ix; }
        }
        sidx = bi;
    }
    __syncthreads();
    int idx = sidx;
    float4 v = *(const float4*)&E[(size_t)idx * D + t * 4];
    *(float4*)&out_an[(size_t)row * D + t * 4] = v;
}

extern "C" void kernel_launch(void* const* d_in, const int* in_sizes, int n_in,
                              void* d_out, int out_size, void* d_ws, size_t ws_size,
                              hipStream_t stream) {
    const float* e_actv = (const float*)d_in[0];
    const float* e_ap   = (const float*)d_in[1];
    const int*   host   = (const int*)d_in[2];
    float* out = (float*)d_out;

    // workspace: sq[N] | pV[N*SPLITS] | pI[N*SPLITS]  (~560 KB)
    float* sq = (float*)d_ws;
    float* pV = sq + N;
    int*   pI = (int*)(pV + (size_t)N * SPLITS);

    copy_kernel<<<2 * N * D / 4 / 256, 256, 0, stream>>>(
        (const float4*)e_actv, (const float4*)e_ap, (float4*)out);
    sqnorm_kernel<<<N, 64, 0, stream>>>(e_actv, sq);
    argmin_kernel<<<(N / BI) * SPLITS, 256, 0, stream>>>(e_actv, host, sq, pV, pI);
    finalize_kernel<<<N, 64, 0, stream>>>(pV, pI, e_actv, out + 2 * (size_t)N * D);
}